// Round 7
// baseline (280.771 us; speedup 1.0000x reference)
//
#include <hip/hip_runtime.h>
#include <hip/hip_fp16.h>
#include <cstdint>
#include <cstddef>

#define NCLS 50000
#define DIM 512
#define NROW 1024
#define NTN 391   // ceil(50000/128)

typedef _Float16 half8 __attribute__((ext_vector_type(8)));
typedef float f32x4 __attribute__((ext_vector_type(4)));

#define AS1(p) ((const __attribute__((address_space(1))) void*)(p))
#define AS3(p) ((__attribute__((address_space(3))) void*)(p))

// ---------------- x: convert to fp16 + row inv-norms (exact f32) ----------------
__global__ void prep_x_kernel(const float* __restrict__ x,
                              __half* __restrict__ xh,
                              float* __restrict__ rn)
{
    int row = blockIdx.x;
    int l = threadIdx.x; // 64 threads = 1 wave
    const float4* xr = (const float4*)(x + (size_t)row * DIM);
    __half2* dst = (__half2*)(xh + (size_t)row * DIM);
    float s = 0.f;
#pragma unroll
    for (int i = 0; i < 2; ++i) {
        int idx = l + i * 64;
        float4 v = xr[idx];
        dst[idx * 2]     = __floats2half2_rn(v.x, v.y);
        dst[idx * 2 + 1] = __floats2half2_rn(v.z, v.w);
        s += v.x * v.x + v.y * v.y + v.z * v.z + v.w * v.w;
    }
#pragma unroll
    for (int off = 32; off > 0; off >>= 1) s += __shfl_down(s, off);
    if (l == 0) rn[row] = rsqrtf(s);
}

// ------- W [512][50000] f32 -> Wt [50000][512] fp16, fused col sum-of-squares ----
__global__ void transpose_w_kernel(const float* __restrict__ W,
                                   __half* __restrict__ Wt,
                                   float* __restrict__ part)
{
    __shared__ float tile[64][65];
    __shared__ float cpart[4][64];
    int n0 = blockIdx.x * 64;
    int k0 = blockIdx.y * 64;
    int t = threadIdx.x; // 256
    int f4 = t & 15;
    int kr = t >> 4;
    int n = n0 + f4 * 4;
    bool ok = (n < NCLS);
#pragma unroll
    for (int i = 0; i < 4; ++i) {
        int k = kr + i * 16;
        float4 v = ok ? *(const float4*)(W + (size_t)(k0 + k) * NCLS + n)
                      : make_float4(0.f, 0.f, 0.f, 0.f);
        tile[k][f4 * 4 + 0] = v.x;
        tile[k][f4 * 4 + 1] = v.y;
        tile[k][f4 * 4 + 2] = v.z;
        tile[k][f4 * 4 + 3] = v.w;
    }
    __syncthreads();
#pragma unroll
    for (int i = 0; i < 8; ++i) {
        int idx = t + i * 256;
        int nn = idx >> 5;
        int kp = idx & 31;
        int gn = n0 + nn;
        if (gn < NCLS) {
            __half2 h = __floats2half2_rn(tile[kp * 2][nn], tile[kp * 2 + 1][nn]);
            *(__half2*)(Wt + (size_t)gn * DIM + k0 + kp * 2) = h;
        }
    }
    {
        int nn = t & 63;
        int seg = t >> 6;
        float s = 0.f;
#pragma unroll
        for (int k = 0; k < 16; ++k) {
            float v = tile[seg * 16 + k][nn];
            s += v * v;
        }
        cpart[seg][nn] = s;
        __syncthreads();
        if (t < 64 && n0 + t < NCLS) {
            part[(size_t)blockIdx.y * NCLS + n0 + t] =
                cpart[0][t] + cpart[1][t] + cpart[2][t] + cpart[3][t];
        }
    }
}

__global__ void make_cn_kernel(const float* __restrict__ part, float* __restrict__ cn)
{
    int c = blockIdx.x * 256 + threadIdx.x;
    if (c >= NCLS) return;
    float s = 0.f;
#pragma unroll
    for (int j = 0; j < 8; ++j) s += part[(size_t)j * NCLS + c];
    cn[c] = rsqrtf(s);
}

// ---------------- labels from one-hot y -----------------------------------------
__global__ void find_labels_kernel(const float4* __restrict__ y4, int* __restrict__ lab)
{
    int i4 = blockIdx.x * 256 + threadIdx.x; // exactly 12,800,000 threads
    float4 v = y4[i4];
    if (v.x != 0.f || v.y != 0.f || v.z != 0.f || v.w != 0.f) {
        long base = (long)i4 * 4;
        if (v.x != 0.f) { long i = base + 0; lab[i / NCLS] = (int)(i % NCLS); }
        if (v.y != 0.f) { long i = base + 1; lab[i / NCLS] = (int)(i % NCLS); }
        if (v.z != 0.f) { long i = base + 2; lab[i / NCLS] = (int)(i % NCLS); }
        if (v.w != 0.f) { long i = base + 3; lab[i / NCLS] = (int)(i % NCLS); }
    }
}

// ---------------- GEMM + arcface + exp, two-pass ---------------------------------
// 128x128 tile, BK=32, 4 waves (2x2). 3-slot LDS ring (48 KB -> 3 blocks/CU),
// counted vmcnt(4), ONE s_barrier per K-iter. Tile t staged at iter t-2.
// Swizzle: data k-block kb stored at pos kb^((row>>1)&3); read reverses. Max
// 2-way bank aliasing (free). PASS 0: rowpart sums only. PASS 1: scaled store.
template<int PASS>
__global__ __launch_bounds__(256, 3) void gemm_arc_kernel(
    const __half* __restrict__ A,
    const __half* __restrict__ Bt,
    const float* __restrict__ rn,
    const float* __restrict__ cn,
    const int* __restrict__ lab,
    const float* __restrict__ rs,
    float* __restrict__ out,
    float* __restrict__ rowpart)
{
    __shared__ __align__(16) char ring[3][16384];  // per slot: A 8 KB + B 8 KB
    __shared__ float rsum[2][128];

    const int tid = threadIdx.x;
    const int wid = tid >> 6;
    const int lane = tid & 63;
    const int wm = wid >> 1;
    const int wn = wid & 1;
    const int rl = lane & 15;
    const int krow = lane >> 4;                       // 0..3
    const int koff = (krow ^ ((rl >> 1) & 3)) * 16;   // de-swizzled 16B k-block

    // bijective XCD swizzle: 3128 = 8 * 391; M-fastest (8 mt per nt) for Bt reuse
    const int b = blockIdx.x;
    const int w = (b & 7) * NTN + (b >> 3);
    const int mt = w & 7;
    const int nt = w >> 3;
    const int tileM = mt * 128;
    const int tileN = nt * 128;

    f32x4 acc[4][4] = {};

    // staging: per K-tile (32 k, 64 B rows), A/B = 8 KB each = 2 calls per wave.
    const int rowl = lane >> 2;                          // 0..15 within 16-row group
    const int sw = (lane & 3) ^ ((lane >> 3) & 3);       // pre-swizzled src k-block
    auto stage = [&](int t) {
        char* base = ring[t % 3];
        const int k0 = t * 32;
#pragma unroll
        for (int c = 0; c < 2; ++c) {
            int r16 = (wid * 2 + c) * 16;                // wave-uniform row base
            const __half* sa = A + (size_t)(tileM + r16 + rowl) * DIM + k0 + sw * 8;
            __builtin_amdgcn_global_load_lds(AS1(sa), AS3(base + r16 * 64), 16, 0, 0);
            int gn = tileN + r16 + rowl;
            if (gn > NCLS - 1) gn = NCLS - 1;            // clamp N edge (masked later)
            const __half* sb = Bt + (size_t)gn * DIM + k0 + sw * 8;
            __builtin_amdgcn_global_load_lds(AS1(sb), AS3(base + 8192 + r16 * 64), 16, 0, 0);
        }
    };

    stage(0); stage(1);      // 8 loads/thread in flight

#pragma unroll 1
    for (int t = 0; t < 16; ++t) {
        // tile t's 4 loads are the oldest; leave tile t+1's 4 in flight
        if (t == 15) asm volatile("s_waitcnt vmcnt(0)" ::: "memory");
        else         asm volatile("s_waitcnt vmcnt(4)" ::: "memory");
        __builtin_amdgcn_s_barrier();                 // tile t visible to all waves
        __builtin_amdgcn_sched_barrier(0);

        if (t + 2 < 16) stage(t + 2);                 // slot of tile t-1 (consumed)

        const char* sb_ = ring[t % 3];
        half8 af[4], bf[4];
#pragma unroll
        for (int m = 0; m < 4; ++m)
            af[m] = *(const half8*)(sb_ + (wm * 64 + m * 16 + rl) * 64 + koff);
#pragma unroll
        for (int n = 0; n < 4; ++n)
            bf[n] = *(const half8*)(sb_ + 8192 + (wn * 64 + n * 16 + rl) * 64 + koff);
        __builtin_amdgcn_s_setprio(1);
#pragma unroll
        for (int m = 0; m < 4; ++m)
#pragma unroll
            for (int n = 0; n < 4; ++n)
                acc[m][n] = __builtin_amdgcn_mfma_f32_16x16x32_f16(af[m], bf[n], acc[m][n], 0, 0, 0);
        __builtin_amdgcn_s_setprio(0);
    }

    // epilogue
    const float cosM = 0.8775825618903728f;
    const float sinM = 0.4794255386042030f;
    const int col_l = rl;
    const int rgrp = krow;

#pragma unroll
    for (int m = 0; m < 4; ++m) {
        int gr0 = tileM + wm * 64 + m * 16 + rgrp * 4;
        float rnv[4]; int labv[4]; float rsv[4];
#pragma unroll
        for (int r = 0; r < 4; ++r) {
            rnv[r] = rn[gr0 + r];
            labv[r] = lab[gr0 + r];
            if (PASS == 1) rsv[r] = rs[gr0 + r];
        }
        float rowacc[4] = {0.f, 0.f, 0.f, 0.f};
#pragma unroll
        for (int n = 0; n < 4; ++n) {
            int gc = tileN + wn * 64 + n * 16 + col_l;
            bool okc = (gc < NCLS);
            float cnv = okc ? cn[gc] : 0.f;
#pragma unroll
            for (int r = 0; r < 4; ++r) {
                float cv = acc[m][n][r] * rnv[r] * cnv;
                float logit;
                if (gc == labv[r]) {
                    float cc = fminf(fmaxf(cv, -1.f + 1e-7f), 1.f - 1e-7f);
                    logit = 64.f * (cc * cosM - sqrtf(1.f - cc * cc) * sinM);
                } else {
                    logit = 64.f * cv;
                }
                float e = __expf(logit);
                if (PASS == 0) {
                    if (okc) rowacc[r] += e;
                } else {
                    if (okc) out[(size_t)(gr0 + r) * NCLS + gc] = e * rsv[r];
                }
            }
        }
        if (PASS == 0) {
#pragma unroll
            for (int r = 0; r < 4; ++r) {
                float s = rowacc[r];
                s += __shfl_xor(s, 1);
                s += __shfl_xor(s, 2);
                s += __shfl_xor(s, 4);
                s += __shfl_xor(s, 8);
                if (col_l == 0) rsum[wn][wm * 64 + m * 16 + rgrp * 4 + r] = s;
            }
        }
    }
    if (PASS == 0) {
        __syncthreads();
        if (tid < 128) {
            float tot = rsum[0][tid] + rsum[1][tid];
            rowpart[(size_t)nt * NROW + tileM + tid] = tot;
        }
    }
}

// ---------------- reduce per-tile row sums -> 1/rowsum ---------------------------
__global__ void reduce_rs_kernel(const float* __restrict__ rowpart, float* __restrict__ rs)
{
    int row = blockIdx.x * 256 + threadIdx.x; // 4 x 256 = 1024
    float s = 0.f;
    for (int t = 0; t < NTN; ++t) s += rowpart[(size_t)t * NROW + row];
    rs[row] = 1.f / s;
}

extern "C" void kernel_launch(void* const* d_in, const int* in_sizes, int n_in,
                              void* d_out, int out_size, void* d_ws, size_t ws_size,
                              hipStream_t stream)
{
    const float* x = (const float*)d_in[0]; // [1024][512]
    const float* y = (const float*)d_in[1]; // [1024][50000] one-hot
    const float* W = (const float*)d_in[2]; // [512][50000]
    float* out = (float*)d_out;             // [1024][50000]

    char* ws = (char*)d_ws;
    __half* Wt     = (__half*)(ws);               // 51,200,000 B : W^T fp16 [50000][512]
    __half* xh     = (__half*)(ws + 51200000);    //  1,048,576 B : x fp16
    float* rn      = (float*) (ws + 52248576);    //      4,096 B : row inv-norms
    float* cn      = (float*) (ws + 52252672);    //    200,000 B : col inv-norms
    // part [8][50000] (consumed by make_cn) then reused as rowpart [391][1024]
    float* part    = (float*) (ws + 52452672);    //  1,601,536 B : union(part, rowpart)
    float* rowpart = part;
    int*   lab     = (int*)   (ws + 54054208);    //      4,096 B : labels
    float* rs      = (float*) (ws + 54058304);    //      4,096 B : 1/rowsum

    hipLaunchKernelGGL(prep_x_kernel, dim3(NROW), dim3(64), 0, stream, x, xh, rn);
    hipLaunchKernelGGL(transpose_w_kernel, dim3(782, 8), dim3(256), 0, stream, W, Wt, part);
    hipLaunchKernelGGL(make_cn_kernel, dim3(196), dim3(256), 0, stream, part, cn);
    hipLaunchKernelGGL(find_labels_kernel, dim3(50000), dim3(256), 0, stream, (const float4*)y, lab);
    hipLaunchKernelGGL(gemm_arc_kernel<0>, dim3(8 * NTN), dim3(256), 0, stream,
                       xh, Wt, rn, cn, lab, rs, out, rowpart);
    hipLaunchKernelGGL(reduce_rs_kernel, dim3(4), dim3(256), 0, stream, rowpart, rs);
    hipLaunchKernelGGL(gemm_arc_kernel<1>, dim3(8 * NTN), dim3(256), 0, stream,
                       xh, Wt, rn, cn, lab, rs, out, rowpart);
}

// Round 8
// 274.394 us; speedup vs baseline: 1.0232x; 1.0232x over previous
//
#include <hip/hip_runtime.h>
#include <hip/hip_fp16.h>
#include <cstdint>
#include <cstddef>

#define NCLS 50000
#define DIM 512
#define NROW 1024
#define NTN 391   // ceil(50000/128)

typedef _Float16 half8 __attribute__((ext_vector_type(8)));
typedef float f32x4 __attribute__((ext_vector_type(4)));

#define AS1(p) ((const __attribute__((address_space(1))) void*)(p))
#define AS3(p) ((__attribute__((address_space(3))) void*)(p))

// ---------------- x: convert to fp16 + row inv-norms (exact f32) ----------------
__global__ void prep_x_kernel(const float* __restrict__ x,
                              __half* __restrict__ xh,
                              float* __restrict__ rn)
{
    int row = blockIdx.x;
    int l = threadIdx.x; // 64 threads = 1 wave
    const float4* xr = (const float4*)(x + (size_t)row * DIM);
    __half2* dst = (__half2*)(xh + (size_t)row * DIM);
    float s = 0.f;
#pragma unroll
    for (int i = 0; i < 2; ++i) {
        int idx = l + i * 64;
        float4 v = xr[idx];
        dst[idx * 2]     = __floats2half2_rn(v.x, v.y);
        dst[idx * 2 + 1] = __floats2half2_rn(v.z, v.w);
        s += v.x * v.x + v.y * v.y + v.z * v.z + v.w * v.w;
    }
#pragma unroll
    for (int off = 32; off > 0; off >>= 1) s += __shfl_down(s, off);
    if (l == 0) rn[row] = rsqrtf(s);
}

// ------- W [512][50000] f32 -> Wt [50000][512] fp16, fused col sum-of-squares ----
__global__ void transpose_w_kernel(const float* __restrict__ W,
                                   __half* __restrict__ Wt,
                                   float* __restrict__ part)
{
    __shared__ float tile[64][65];
    __shared__ float cpart[4][64];
    int n0 = blockIdx.x * 64;
    int k0 = blockIdx.y * 64;
    int t = threadIdx.x; // 256
    int f4 = t & 15;
    int kr = t >> 4;
    int n = n0 + f4 * 4;
    bool ok = (n < NCLS);
#pragma unroll
    for (int i = 0; i < 4; ++i) {
        int k = kr + i * 16;
        float4 v = ok ? *(const float4*)(W + (size_t)(k0 + k) * NCLS + n)
                      : make_float4(0.f, 0.f, 0.f, 0.f);
        tile[k][f4 * 4 + 0] = v.x;
        tile[k][f4 * 4 + 1] = v.y;
        tile[k][f4 * 4 + 2] = v.z;
        tile[k][f4 * 4 + 3] = v.w;
    }
    __syncthreads();
#pragma unroll
    for (int i = 0; i < 8; ++i) {
        int idx = t + i * 256;
        int nn = idx >> 5;
        int kp = idx & 31;
        int gn = n0 + nn;
        if (gn < NCLS) {
            __half2 h = __floats2half2_rn(tile[kp * 2][nn], tile[kp * 2 + 1][nn]);
            *(__half2*)(Wt + (size_t)gn * DIM + k0 + kp * 2) = h;
        }
    }
    {
        int nn = t & 63;
        int seg = t >> 6;
        float s = 0.f;
#pragma unroll
        for (int k = 0; k < 16; ++k) {
            float v = tile[seg * 16 + k][nn];
            s += v * v;
        }
        cpart[seg][nn] = s;
        __syncthreads();
        if (t < 64 && n0 + t < NCLS) {
            part[(size_t)blockIdx.y * NCLS + n0 + t] =
                cpart[0][t] + cpart[1][t] + cpart[2][t] + cpart[3][t];
        }
    }
}

__global__ void make_cn_kernel(const float* __restrict__ part, float* __restrict__ cn)
{
    int c = blockIdx.x * 256 + threadIdx.x;
    if (c >= NCLS) return;
    float s = 0.f;
#pragma unroll
    for (int j = 0; j < 8; ++j) s += part[(size_t)j * NCLS + c];
    cn[c] = rsqrtf(s);
}

// ---------------- GEMM + arcface + exp, two-pass ---------------------------------
// m97 structure (round-5 proven): 128x128 tile, BK=64, 4 waves (2x2), single
// 32 KB LDS buffer, stage->sync->compute->sync, 4 blocks/CU.
// PASS 0: fused y-tile scan (coalesced, exact partition) -> labloc LDS + lab[];
//         margin applied via labloc; writes rowpart sums only.
// PASS 1: margin via lab[]; scaled e*rs stores repacked through LDS -> float4.
template<int PASS>
__global__ __launch_bounds__(256, 4) void gemm_arc_kernel(
    const __half* __restrict__ A,
    const __half* __restrict__ Bt,
    const float* __restrict__ rn,
    const float* __restrict__ cn,
    const float* __restrict__ y,
    int* __restrict__ lab,
    const float* __restrict__ rs,
    float* __restrict__ out,
    float* __restrict__ rowpart)
{
    __shared__ __align__(16) __half As[128 * 64];
    __shared__ __align__(16) __half Bs[128 * 64];
    __shared__ float rsum[2][128];
    __shared__ int labloc[128];

    const int tid = threadIdx.x;
    const int wid = tid >> 6;
    const int lane = tid & 63;
    const int wm = wid >> 1;
    const int wn = wid & 1;

    // bijective XCD swizzle: 3128 = 8 * 391; M-fastest (8 mt per nt) for Bt reuse
    const int b = blockIdx.x;
    const int w = (b & 7) * NTN + (b >> 3);
    const int mt = w & 7;
    const int nt = w >> 3;
    const int tileM = mt * 128;
    const int tileN = nt * 128;

    const int srow = lane >> 3;            // 0..7
    const int sblk = (lane & 7) ^ srow;    // pre-swizzled global 16B-block

    if (PASS == 0 && tid < 128) labloc[tid] = -1;   // covered by K-loop barriers

    f32x4 acc[4][4] = {};

    auto stage = [&](int k0) {
#pragma unroll
        for (int c = 0; c < 4; ++c) {
            int chunk = wid * 4 + c;       // wave-uniform
            int row = chunk * 8 + srow;    // 0..127
            const __half* sa = A + (size_t)(tileM + row) * DIM + k0 + sblk * 8;
            __builtin_amdgcn_global_load_lds(AS1(sa), AS3((char*)As + chunk * 1024), 16, 0, 0);
            int gn = tileN + row;
            if (gn > NCLS - 1) gn = NCLS - 1; // clamp N edge (masked later)
            const __half* sb = Bt + (size_t)gn * DIM + k0 + sblk * 8;
            __builtin_amdgcn_global_load_lds(AS1(sb), AS3((char*)Bs + chunk * 1024), 16, 0, 0);
        }
    };

    auto compute = [&]() {
        const int krow = lane >> 4; // 0..3
        const int rl = lane & 15;
#pragma unroll
        for (int kk = 0; kk < 2; ++kk) {
            half8 af[4], bf[4];
#pragma unroll
            for (int m = 0; m < 4; ++m) {
                int r = wm * 64 + m * 16 + rl;
                int kb = (kk * 4 + krow) ^ (r & 7); // XOR de-swizzle on read
                af[m] = *(const half8*)((const char*)As + r * 128 + kb * 16);
            }
#pragma unroll
            for (int n = 0; n < 4; ++n) {
                int r = wn * 64 + n * 16 + rl;
                int kb = (kk * 4 + krow) ^ (r & 7);
                bf[n] = *(const half8*)((const char*)Bs + r * 128 + kb * 16);
            }
#pragma unroll
            for (int m = 0; m < 4; ++m)
#pragma unroll
                for (int n = 0; n < 4; ++n)
                    acc[m][n] = __builtin_amdgcn_mfma_f32_16x16x32_f16(af[m], bf[n], acc[m][n], 0, 0, 0);
        }
    };

    // m97 loop: single buffer, drain hidden by 4 co-resident blocks
#pragma unroll 1
    for (int k0 = 0; k0 < DIM; k0 += 64) {
        stage(k0);
        __syncthreads();
        compute();
        __syncthreads();
    }

    if (PASS == 0) {
        // y-tile scan: this block's 128 rows x 128 cols, float4-coalesced.
        // Exact partition of y across blocks; at most one hit per row here.
#pragma unroll
        for (int i = 0; i < 16; ++i) {
            int idx = tid + i * 256;       // 0..4095
            int row = idx >> 5;            // 0..127
            int c4 = idx & 31;
            int gc = tileN + c4 * 4;
            if (gc < NCLS) {
                float4 v = *(const float4*)(y + (size_t)(tileM + row) * NCLS + gc);
                int hit = -1;
                if (v.x != 0.f) hit = gc;
                if (v.y != 0.f) hit = gc + 1;
                if (v.z != 0.f) hit = gc + 2;
                if (v.w != 0.f) hit = gc + 3;
                if (hit >= 0) {
                    labloc[row] = hit;
                    lab[tileM + row] = hit;   // unique writer; consumed by pass 1
                }
            }
        }
        __syncthreads();
    }

    // epilogue
    const float cosM = 0.8775825618903728f;
    const float sinM = 0.4794255386042030f;
    const int col_l = lane & 15;
    const int rgrp = lane >> 4;
    float* buf = (float*)As;   // PASS 1 repack buffer [32][128] f32 (16 KB)

#pragma unroll
    for (int m = 0; m < 4; ++m) {
        int lr0 = wm * 64 + m * 16 + rgrp * 4;   // local row base 0..127
        int gr0 = tileM + lr0;
        float rnv[4]; int labv[4]; float rsv[4];
#pragma unroll
        for (int r = 0; r < 4; ++r) {
            rnv[r] = rn[gr0 + r];
            if (PASS == 0) labv[r] = labloc[lr0 + r];
            else { labv[r] = lab[gr0 + r]; rsv[r] = rs[gr0 + r]; }
        }
        float rowacc[4] = {0.f, 0.f, 0.f, 0.f};
#pragma unroll
        for (int n = 0; n < 4; ++n) {
            int gc = tileN + wn * 64 + n * 16 + col_l;
            bool okc = (gc < NCLS);
            float cnv = okc ? cn[gc] : 0.f;
#pragma unroll
            for (int r = 0; r < 4; ++r) {
                float cv = acc[m][n][r] * rnv[r] * cnv;
                float logit;
                if (gc == labv[r]) {
                    float cc = fminf(fmaxf(cv, -1.f + 1e-7f), 1.f - 1e-7f);
                    logit = 64.f * (cc * cosM - sqrtf(1.f - cc * cc) * sinM);
                } else {
                    logit = 64.f * cv;
                }
                float e = __expf(logit);
                if (PASS == 0) {
                    if (okc) rowacc[r] += e;
                } else {
                    // local row (wm*16 + rgrp*4 + r) in 32-row slab, col 0..127
                    buf[(wm * 16 + rgrp * 4 + r) * 128 + wn * 64 + n * 16 + col_l] = e * rsv[r];
                }
            }
        }
        if (PASS == 0) {
#pragma unroll
            for (int r = 0; r < 4; ++r) {
                float s = rowacc[r];
                s += __shfl_xor(s, 1);
                s += __shfl_xor(s, 2);
                s += __shfl_xor(s, 4);
                s += __shfl_xor(s, 8);
                if (col_l == 0) rsum[wn][lr0 + r] = s;
            }
        } else {
            __syncthreads();   // buf slab complete
            // cooperative coalesced float4 store: 32 rows x 128 cols
#pragma unroll
            for (int i = 0; i < 4; ++i) {
                int idx = tid + i * 256;          // 0..1023
                int lr = idx >> 5;                // 0..31
                int c4 = idx & 31;
                int gr = tileM + (lr >> 4) * 64 + m * 16 + (lr & 15);
                int gcl = tileN + c4 * 4;
                if (gcl < NCLS)
                    *(float4*)(out + (size_t)gr * NCLS + gcl) = ((float4*)buf)[idx];
            }
            __syncthreads();   // before next m overwrites buf
        }
    }
    if (PASS == 0) {
        __syncthreads();
        if (tid < 128) {
            float tot = rsum[0][tid] + rsum[1][tid];
            rowpart[(size_t)nt * NROW + tileM + tid] = tot;
        }
    }
}

// ---------------- reduce per-tile row sums -> 1/rowsum ---------------------------
__global__ void reduce_rs_kernel(const float* __restrict__ rowpart, float* __restrict__ rs)
{
    int row = blockIdx.x * 256 + threadIdx.x; // 4 x 256 = 1024
    float s = 0.f;
    for (int t = 0; t < NTN; ++t) s += rowpart[(size_t)t * NROW + row];
    rs[row] = 1.f / s;
}

extern "C" void kernel_launch(void* const* d_in, const int* in_sizes, int n_in,
                              void* d_out, int out_size, void* d_ws, size_t ws_size,
                              hipStream_t stream)
{
    const float* x = (const float*)d_in[0]; // [1024][512]
    const float* y = (const float*)d_in[1]; // [1024][50000] one-hot
    const float* W = (const float*)d_in[2]; // [512][50000]
    float* out = (float*)d_out;             // [1024][50000]

    char* ws = (char*)d_ws;
    __half* Wt     = (__half*)(ws);               // 51,200,000 B : W^T fp16 [50000][512]
    __half* xh     = (__half*)(ws + 51200000);    //  1,048,576 B : x fp16
    float* rn      = (float*) (ws + 52248576);    //      4,096 B : row inv-norms
    float* cn      = (float*) (ws + 52252672);    //    200,000 B : col inv-norms
    // part [8][50000] (consumed by make_cn) then reused as rowpart [391][1024]
    float* part    = (float*) (ws + 52452672);    //  1,601,536 B : union(part, rowpart)
    float* rowpart = part;
    int*   lab     = (int*)   (ws + 54054208);    //      4,096 B : labels
    float* rs      = (float*) (ws + 54058304);    //      4,096 B : 1/rowsum

    hipLaunchKernelGGL(prep_x_kernel, dim3(NROW), dim3(64), 0, stream, x, xh, rn);
    hipLaunchKernelGGL(transpose_w_kernel, dim3(782, 8), dim3(256), 0, stream, W, Wt, part);
    hipLaunchKernelGGL(make_cn_kernel, dim3(196), dim3(256), 0, stream, part, cn);
    hipLaunchKernelGGL(gemm_arc_kernel<0>, dim3(8 * NTN), dim3(256), 0, stream,
                       xh, Wt, rn, cn, y, lab, rs, out, rowpart);
    hipLaunchKernelGGL(reduce_rs_kernel, dim3(4), dim3(256), 0, stream, rowpart, rs);
    hipLaunchKernelGGL(gemm_arc_kernel<1>, dim3(8 * NTN), dim3(256), 0, stream,
                       xh, Wt, rn, cn, y, lab, rs, out, rowpart);
}

// Round 9
// 254.996 us; speedup vs baseline: 1.1011x; 1.0761x over previous
//
#include <hip/hip_runtime.h>
#include <hip/hip_fp16.h>
#include <cstdint>
#include <cstddef>

#define NCLS 50000
#define DIM 512
#define NROW 1024
#define NTN 391   // ceil(50000/128)

typedef _Float16 half8 __attribute__((ext_vector_type(8)));
typedef float f32x4 __attribute__((ext_vector_type(4)));

#define AS1(p) ((const __attribute__((address_space(1))) void*)(p))
#define AS3(p) ((__attribute__((address_space(3))) void*)(p))

// ---------------- x: convert to fp16 + row inv-norms (exact f32) ----------------
__global__ void prep_x_kernel(const float* __restrict__ x,
                              __half* __restrict__ xh,
                              float* __restrict__ rn)
{
    int row = blockIdx.x;
    int l = threadIdx.x; // 64 threads = 1 wave
    const float4* xr = (const float4*)(x + (size_t)row * DIM);
    __half2* dst = (__half2*)(xh + (size_t)row * DIM);
    float s = 0.f;
#pragma unroll
    for (int i = 0; i < 2; ++i) {
        int idx = l + i * 64;
        float4 v = xr[idx];
        dst[idx * 2]     = __floats2half2_rn(v.x, v.y);
        dst[idx * 2 + 1] = __floats2half2_rn(v.z, v.w);
        s += v.x * v.x + v.y * v.y + v.z * v.z + v.w * v.w;
    }
#pragma unroll
    for (int off = 32; off > 0; off >>= 1) s += __shfl_down(s, off);
    if (l == 0) rn[row] = rsqrtf(s);
}

// ------- W [512][50000] f32 -> Wt [50000][512] fp16, fused col sum-of-squares ----
__global__ void transpose_w_kernel(const float* __restrict__ W,
                                   __half* __restrict__ Wt,
                                   float* __restrict__ part)
{
    __shared__ float tile[64][65];
    __shared__ float cpart[4][64];
    int n0 = blockIdx.x * 64;
    int k0 = blockIdx.y * 64;
    int t = threadIdx.x; // 256
    int f4 = t & 15;
    int kr = t >> 4;
    int n = n0 + f4 * 4;
    bool ok = (n < NCLS);
#pragma unroll
    for (int i = 0; i < 4; ++i) {
        int k = kr + i * 16;
        float4 v = ok ? *(const float4*)(W + (size_t)(k0 + k) * NCLS + n)
                      : make_float4(0.f, 0.f, 0.f, 0.f);
        tile[k][f4 * 4 + 0] = v.x;
        tile[k][f4 * 4 + 1] = v.y;
        tile[k][f4 * 4 + 2] = v.z;
        tile[k][f4 * 4 + 3] = v.w;
    }
    __syncthreads();
#pragma unroll
    for (int i = 0; i < 8; ++i) {
        int idx = t + i * 256;
        int nn = idx >> 5;
        int kp = idx & 31;
        int gn = n0 + nn;
        if (gn < NCLS) {
            __half2 h = __floats2half2_rn(tile[kp * 2][nn], tile[kp * 2 + 1][nn]);
            *(__half2*)(Wt + (size_t)gn * DIM + k0 + kp * 2) = h;
        }
    }
    {
        int nn = t & 63;
        int seg = t >> 6;
        float s = 0.f;
#pragma unroll
        for (int k = 0; k < 16; ++k) {
            float v = tile[seg * 16 + k][nn];
            s += v * v;
        }
        cpart[seg][nn] = s;
        __syncthreads();
        if (t < 64 && n0 + t < NCLS) {
            part[(size_t)blockIdx.y * NCLS + n0 + t] =
                cpart[0][t] + cpart[1][t] + cpart[2][t] + cpart[3][t];
        }
    }
}

__global__ void make_cn_kernel(const float* __restrict__ part, float* __restrict__ cn)
{
    int c = blockIdx.x * 256 + threadIdx.x;
    if (c >= NCLS) return;
    float s = 0.f;
#pragma unroll
    for (int j = 0; j < 8; ++j) s += part[(size_t)j * NCLS + c];
    cn[c] = rsqrtf(s);
}

// ---------------- labels from one-hot y (streaming, coalesced) -------------------
__global__ void find_labels_kernel(const float4* __restrict__ y4, int* __restrict__ lab)
{
    int i4 = blockIdx.x * 256 + threadIdx.x; // exactly 12,800,000 threads
    float4 v = y4[i4];
    if (v.x != 0.f || v.y != 0.f || v.z != 0.f || v.w != 0.f) {
        long base = (long)i4 * 4;
        if (v.x != 0.f) { long i = base + 0; lab[i / NCLS] = (int)(i % NCLS); }
        if (v.y != 0.f) { long i = base + 1; lab[i / NCLS] = (int)(i % NCLS); }
        if (v.z != 0.f) { long i = base + 2; lab[i / NCLS] = (int)(i % NCLS); }
        if (v.w != 0.f) { long i = base + 3; lab[i / NCLS] = (int)(i % NCLS); }
    }
}

// ---------------- GEMM + arcface + exp, two-pass ---------------------------------
// m97 structure (round-5 proven): 128x128 tile, BK=64, 4 waves (2x2), single
// 32 KB LDS buffer, stage->sync->compute->sync, 4 blocks/CU.
// PASS 0: margin via lab[]; writes rowpart sums only.
// PASS 1: margin via lab[]; e*rs stores repacked through LDS -> float4.
template<int PASS>
__global__ __launch_bounds__(256, 4) void gemm_arc_kernel(
    const __half* __restrict__ A,
    const __half* __restrict__ Bt,
    const float* __restrict__ rn,
    const float* __restrict__ cn,
    const int* __restrict__ lab,
    const float* __restrict__ rs,
    float* __restrict__ out,
    float* __restrict__ rowpart)
{
    __shared__ __align__(16) __half As[128 * 64];
    __shared__ __align__(16) __half Bs[128 * 64];
    __shared__ float rsum[2][128];

    const int tid = threadIdx.x;
    const int wid = tid >> 6;
    const int lane = tid & 63;
    const int wm = wid >> 1;
    const int wn = wid & 1;

    // bijective XCD swizzle: 3128 = 8 * 391; M-fastest (8 mt per nt) for Bt reuse
    const int b = blockIdx.x;
    const int w = (b & 7) * NTN + (b >> 3);
    const int mt = w & 7;
    const int nt = w >> 3;
    const int tileM = mt * 128;
    const int tileN = nt * 128;

    const int srow = lane >> 3;            // 0..7
    const int sblk = (lane & 7) ^ srow;    // pre-swizzled global 16B-block

    f32x4 acc[4][4] = {};

    auto stage = [&](int k0) {
#pragma unroll
        for (int c = 0; c < 4; ++c) {
            int chunk = wid * 4 + c;       // wave-uniform
            int row = chunk * 8 + srow;    // 0..127
            const __half* sa = A + (size_t)(tileM + row) * DIM + k0 + sblk * 8;
            __builtin_amdgcn_global_load_lds(AS1(sa), AS3((char*)As + chunk * 1024), 16, 0, 0);
            int gn = tileN + row;
            if (gn > NCLS - 1) gn = NCLS - 1; // clamp N edge (masked later)
            const __half* sb = Bt + (size_t)gn * DIM + k0 + sblk * 8;
            __builtin_amdgcn_global_load_lds(AS1(sb), AS3((char*)Bs + chunk * 1024), 16, 0, 0);
        }
    };

    auto compute = [&]() {
        const int krow = lane >> 4; // 0..3
        const int rl = lane & 15;
#pragma unroll
        for (int kk = 0; kk < 2; ++kk) {
            half8 af[4], bf[4];
#pragma unroll
            for (int m = 0; m < 4; ++m) {
                int r = wm * 64 + m * 16 + rl;
                int kb = (kk * 4 + krow) ^ (r & 7); // XOR de-swizzle on read
                af[m] = *(const half8*)((const char*)As + r * 128 + kb * 16);
            }
#pragma unroll
            for (int n = 0; n < 4; ++n) {
                int r = wn * 64 + n * 16 + rl;
                int kb = (kk * 4 + krow) ^ (r & 7);
                bf[n] = *(const half8*)((const char*)Bs + r * 128 + kb * 16);
            }
#pragma unroll
            for (int m = 0; m < 4; ++m)
#pragma unroll
                for (int n = 0; n < 4; ++n)
                    acc[m][n] = __builtin_amdgcn_mfma_f32_16x16x32_f16(af[m], bf[n], acc[m][n], 0, 0, 0);
        }
    };

    // m97 loop: single buffer, drain hidden by 4 co-resident blocks
#pragma unroll 1
    for (int k0 = 0; k0 < DIM; k0 += 64) {
        stage(k0);
        __syncthreads();
        compute();
        __syncthreads();
    }

    // epilogue
    const float cosM = 0.8775825618903728f;
    const float sinM = 0.4794255386042030f;
    const int col_l = lane & 15;
    const int rgrp = lane >> 4;
    float* buf = (float*)As;   // PASS 1 repack buffer [32][128] f32 (16 KB)

#pragma unroll
    for (int m = 0; m < 4; ++m) {
        int lr0 = wm * 64 + m * 16 + rgrp * 4;   // local row base 0..127
        int gr0 = tileM + lr0;
        float rnv[4]; int labv[4]; float rsv[4];
#pragma unroll
        for (int r = 0; r < 4; ++r) {
            rnv[r] = rn[gr0 + r];
            labv[r] = lab[gr0 + r];
            if (PASS == 1) rsv[r] = rs[gr0 + r];
        }
        float rowacc[4] = {0.f, 0.f, 0.f, 0.f};
#pragma unroll
        for (int n = 0; n < 4; ++n) {
            int gc = tileN + wn * 64 + n * 16 + col_l;
            bool okc = (gc < NCLS);
            float cnv = okc ? cn[gc] : 0.f;
#pragma unroll
            for (int r = 0; r < 4; ++r) {
                float cv = acc[m][n][r] * rnv[r] * cnv;
                float logit;
                if (gc == labv[r]) {
                    float cc = fminf(fmaxf(cv, -1.f + 1e-7f), 1.f - 1e-7f);
                    logit = 64.f * (cc * cosM - sqrtf(1.f - cc * cc) * sinM);
                } else {
                    logit = 64.f * cv;
                }
                float e = __expf(logit);
                if (PASS == 0) {
                    if (okc) rowacc[r] += e;
                } else {
                    // local row (wm*16 + rgrp*4 + r) in 32-row slab, col 0..127
                    buf[(wm * 16 + rgrp * 4 + r) * 128 + wn * 64 + n * 16 + col_l] = e * rsv[r];
                }
            }
        }
        if (PASS == 0) {
#pragma unroll
            for (int r = 0; r < 4; ++r) {
                float s = rowacc[r];
                s += __shfl_xor(s, 1);
                s += __shfl_xor(s, 2);
                s += __shfl_xor(s, 4);
                s += __shfl_xor(s, 8);
                if (col_l == 0) rsum[wn][lr0 + r] = s;
            }
        } else {
            __syncthreads();   // buf slab complete
            // cooperative coalesced float4 store: 32 rows x 128 cols
#pragma unroll
            for (int i = 0; i < 4; ++i) {
                int idx = tid + i * 256;          // 0..1023
                int lr = idx >> 5;                // 0..31
                int c4 = idx & 31;
                int gr = tileM + (lr >> 4) * 64 + m * 16 + (lr & 15);
                int gcl = tileN + c4 * 4;
                if (gcl < NCLS)
                    *(float4*)(out + (size_t)gr * NCLS + gcl) = ((float4*)buf)[idx];
            }
            __syncthreads();   // before next m overwrites buf
        }
    }
    if (PASS == 0) {
        __syncthreads();
        if (tid < 128) {
            float tot = rsum[0][tid] + rsum[1][tid];
            rowpart[(size_t)nt * NROW + tileM + tid] = tot;
        }
    }
}

// ---------------- reduce per-tile row sums -> 1/rowsum ---------------------------
__global__ void reduce_rs_kernel(const float* __restrict__ rowpart, float* __restrict__ rs)
{
    int row = blockIdx.x * 256 + threadIdx.x; // 4 x 256 = 1024
    float s = 0.f;
    for (int t = 0; t < NTN; ++t) s += rowpart[(size_t)t * NROW + row];
    rs[row] = 1.f / s;
}

extern "C" void kernel_launch(void* const* d_in, const int* in_sizes, int n_in,
                              void* d_out, int out_size, void* d_ws, size_t ws_size,
                              hipStream_t stream)
{
    const float* x = (const float*)d_in[0]; // [1024][512]
    const float* y = (const float*)d_in[1]; // [1024][50000] one-hot
    const float* W = (const float*)d_in[2]; // [512][50000]
    float* out = (float*)d_out;             // [1024][50000]

    char* ws = (char*)d_ws;
    __half* Wt     = (__half*)(ws);               // 51,200,000 B : W^T fp16 [50000][512]
    __half* xh     = (__half*)(ws + 51200000);    //  1,048,576 B : x fp16
    float* rn      = (float*) (ws + 52248576);    //      4,096 B : row inv-norms
    float* cn      = (float*) (ws + 52252672);    //    200,000 B : col inv-norms
    // part [8][50000] (consumed by make_cn) then reused as rowpart [391][1024]
    float* part    = (float*) (ws + 52452672);    //  1,601,536 B : union(part, rowpart)
    float* rowpart = part;
    int*   lab     = (int*)   (ws + 54054208);    //      4,096 B : labels
    float* rs      = (float*) (ws + 54058304);    //      4,096 B : 1/rowsum

    hipLaunchKernelGGL(prep_x_kernel, dim3(NROW), dim3(64), 0, stream, x, xh, rn);
    hipLaunchKernelGGL(transpose_w_kernel, dim3(782, 8), dim3(256), 0, stream, W, Wt, part);
    hipLaunchKernelGGL(make_cn_kernel, dim3(196), dim3(256), 0, stream, part, cn);
    hipLaunchKernelGGL(find_labels_kernel, dim3(50000), dim3(256), 0, stream, (const float4*)y, lab);
    hipLaunchKernelGGL(gemm_arc_kernel<0>, dim3(8 * NTN), dim3(256), 0, stream,
                       xh, Wt, rn, cn, lab, rs, out, rowpart);
    hipLaunchKernelGGL(reduce_rs_kernel, dim3(4), dim3(256), 0, stream, rowpart, rs);
    hipLaunchKernelGGL(gemm_arc_kernel<1>, dim3(8 * NTN), dim3(256), 0, stream,
                       xh, Wt, rn, cn, lab, rs, out, rowpart);
}